// Round 15
// baseline (192.136 us; speedup 1.0000x reference)
//
#include <hip/hip_runtime.h>
#include <hip/hip_bf16.h>

#define DEV __device__ __forceinline__

typedef float f32x4 __attribute__((ext_vector_type(4)));
typedef float f32x16 __attribute__((ext_vector_type(16)));
typedef short s16x8 __attribute__((ext_vector_type(8)));
typedef unsigned short u16x4 __attribute__((ext_vector_type(4)));
typedef __bf16 bf16x8 __attribute__((ext_vector_type(8)));

DEV bf16x8 as_bf16(s16x8 v) { return __builtin_bit_cast(bf16x8, v); }

DEV unsigned short f2bf(float f) {
    union { __hip_bfloat16 h; unsigned short u; } c;
    c.h = __float2bfloat16(f);
    return c.u;
}

DEV float bf2f(unsigned short u) {
    return __builtin_bit_cast(float, (unsigned)u << 16);
}

// RNE f32->bf16 pair pack (finite inputs only)
DEV unsigned f2bf2(float lo, float hi) {
    unsigned ulo = __builtin_bit_cast(unsigned, lo);
    unsigned uhi = __builtin_bit_cast(unsigned, hi);
    ulo = (ulo + 0x7fffu + ((ulo >> 16) & 1u)) >> 16;
    uhi = (uhi + 0x7fffu + ((uhi >> 16) & 1u)) & 0xffff0000u;
    return ulo | uhi;
}

DEV float wave_sum64(float v) {
#pragma unroll
    for (int m = 1; m < 64; m <<= 1) v += __shfl_xor(v, m, 64);
    return v;
}

// 3-bit rotate-left; 16B-slot swizzle
DEV int rot3(int r) { return ((r << 1) | (r >> 2)) & 7; }

constexpr float QSCL = (float)(1.4426950408889634 / 5.656854249492381);  // log2(e)/sqrt(32)

// ---------------------------------------------------------------------------
// Setup (merged): [0,2048) mask -> bits; [2048,4096) ctx+preLN -> x;
// [4096,4352) weight prep via coalesced 32x32 LDS tile transpose;
// bx==4352: bias concat + tail-counter reset
// ---------------------------------------------------------------------------
__global__ __launch_bounds__(256) void gace_setup_k(
    const float* __restrict__ am, unsigned long long* __restrict__ bits,
    const float* __restrict__ task, const float* __restrict__ priv, const float* __restrict__ dag,
    const float* __restrict__ tW, const float* __restrict__ tb,
    const float* __restrict__ pW, const float* __restrict__ pb,
    const float* __restrict__ dW, const float* __restrict__ db,
    const float* __restrict__ pre_g, const float* __restrict__ pre_b,
    float* __restrict__ x,
    const float* __restrict__ qW, const float* __restrict__ kW,
    const float* __restrict__ vW, const float* __restrict__ oW,
    const float* __restrict__ f1W, const float* __restrict__ f2W,
    const float* __restrict__ qb, const float* __restrict__ kb,
    const float* __restrict__ vb,
    unsigned short* __restrict__ wbf, float* __restrict__ bcat,
    unsigned* __restrict__ cnt)
{
    __shared__ unsigned short tileS[32][33];
    const int bx = blockIdx.x;
    const int tid = threadIdx.x, wid = tid >> 6, l = tid & 63;
    if (bx < 2048) {
        // mask quirks: no-masked row -> set diag (need_fix); all-masked row ->
        // clear diag (== torch diag-score-0 fixup in softmax-weight space)
        const int row = bx * 4 + wid;
        const float* mrow = am + (size_t)row * 2048;
        unsigned long long myword = 0, orAll = 0, andAll = ~0ull;
#pragma unroll 4
        for (int w = 0; w < 32; ++w) {
            unsigned long long bal = __ballot(mrow[w * 64 + l] > 0.5f);
            if (w == l) myword = bal;
            orAll |= bal; andAll &= bal;
        }
        const int lrow = row & 2047;
        const int dw = lrow >> 6, dbit = lrow & 63;
        if (l == dw) {
            if (orAll == 0ull) myword |= (1ull << dbit);
            else if (andAll == ~0ull) myword &= ~(1ull << dbit);
        }
        if (l < 32) bits[(size_t)row * 32 + l] = myword;
        return;
    }
    if (bx < 4096) {
        const int row = (bx - 2048) * 4 + wid;
        const int d0 = l, d1 = l + 64;
        float a0 = tb[d0] + pb[d0] + db[d0];
        float a1 = tb[d1] + pb[d1] + db[d1];
        const float* tf = task + (size_t)row * 15;
#pragma unroll
        for (int j = 0; j < 15; ++j) { const float t = tf[j]; a0 += t * tW[j * 128 + d0]; a1 += t * tW[j * 128 + d1]; }
        const float* pf = priv + (size_t)row * 6;
#pragma unroll
        for (int j = 0; j < 6; ++j) { const float t = pf[j]; a0 += t * pW[j * 128 + d0]; a1 += t * pW[j * 128 + d1]; }
        const float* df = dag + (size_t)row * 4;
#pragma unroll
        for (int j = 0; j < 4; ++j) { const float t = df[j]; a0 += t * dW[j * 128 + d0]; a1 += t * dW[j * 128 + d1]; }
        const float s = wave_sum64(a0 + a1);
        const float mean = s * (1.f / 128.f);
        const float e0 = a0 - mean, e1 = a1 - mean;
        const float s2 = wave_sum64(e0 * e0 + e1 * e1);
        const float rs = rsqrtf(s2 * (1.f / 128.f) + 1e-5f);
        x[(size_t)row * 128 + d0] = e0 * rs * pre_g[d0] + pre_b[d0];
        x[(size_t)row * 128 + d1] = e1 * rs * pre_g[d1] + pre_b[d1];
        return;
    }
    if (bx < 4352) {
        // ---- weight prep: one 32x32 tile per block, coalesced both sides
        const int t = bx - 4096;                  // 0..255
        const int i = t >> 7, tl = t & 127;
        const float* src; int K_, N_, off, kt, nt; float scl = 1.0f;
        if (tl < 64) {
            const int y = tl >> 4, sub = tl & 15;
            kt = sub >> 2; nt = sub & 3;
            K_ = 128; N_ = 128;
            switch (y) {
                case 0:  src = qW; off = 0;     scl = QSCL; break;
                case 1:  src = kW; off = 16384; break;
                case 2:  src = vW; off = 32768; break;
                default: src = oW; off = 49152; break;
            }
        } else if (tl < 96) {
            const int sub = tl - 64; kt = sub >> 3; nt = sub & 7;
            K_ = 128; N_ = 256; src = f1W; off = 65536;
        } else {
            const int sub = tl - 96; kt = sub >> 2; nt = sub & 3;
            K_ = 256; N_ = 128; src = f2W; off = 98304;
        }
        const int per = K_ * N_;
        const int k0 = kt * 32, n0 = nt * 32;
        const int rr = tid >> 5, cc = tid & 31;
#pragma unroll
        for (int it = 0; it < 4; ++it) {
            const int r = it * 8 + rr;
            tileS[r][cc] = f2bf(src[(size_t)i * per + (size_t)(k0 + r) * N_ + n0 + cc] * scl);
        }
        __syncthreads();
#pragma unroll
        for (int it = 0; it < 4; ++it) {
            const int n = it * 8 + rr;
            wbf[(size_t)i * 131072 + off + (size_t)(n0 + n) * K_ + k0 + cc] = tileS[cc][n];
        }
        return;
    }
    // ---- bias concat + counter reset
    if (tid == 0) cnt[0] = 0u;
    for (int j = tid; j < 768; j += 256) {
        const int i = j / 384, jj = j % 384;
        float v;
        if (jj < 128)      v = qb[i * 128 + jj] * QSCL;
        else if (jj < 256) v = kb[i * 128 + jj - 128];
        else               v = vb[i * 128 + jj - 256];
        bcat[j] = v;
    }
}

// ---------------------------------------------------------------------------
// qkv GEMM with fused LN1, no LDS.  V cols (n>=256) stored transposed.
// (layer 0 only; layer 1's qkv is fused into gace_post2_k<1,0>)
// ---------------------------------------------------------------------------
__global__ __launch_bounds__(256) void gace_qkv_k(
    const float* __restrict__ xin,
    const float* __restrict__ gam, const float* __restrict__ bet,
    const unsigned short* __restrict__ Wt,
    const float* __restrict__ bias,
    unsigned short* __restrict__ qk, unsigned short* __restrict__ vtbuf)
{
    const int tid = threadIdx.x;
    const int wid = tid >> 6, l = tid & 63;
    const int g = (l >> 4) & 3, c16 = l & 15;
    const int m0 = blockIdx.x * 64 + wid * 16;
    const int n0 = blockIdx.y * 64;
    const int arow = m0 + c16;

    float v[4][8];
#pragma unroll
    for (int kc = 0; kc < 4; ++kc) {
        const f32x4 a0 = *(const f32x4*)&xin[(size_t)arow * 128 + kc * 32 + 8 * g];
        const f32x4 a1 = *(const f32x4*)&xin[(size_t)arow * 128 + kc * 32 + 8 * g + 4];
#pragma unroll
        for (int e = 0; e < 4; ++e) { v[kc][e] = a0[e]; v[kc][4 + e] = a1[e]; }
    }
    float s = 0.f;
#pragma unroll
    for (int kc = 0; kc < 4; ++kc)
#pragma unroll
        for (int e = 0; e < 8; ++e) s += v[kc][e];
    s += __shfl_xor(s, 16, 64); s += __shfl_xor(s, 32, 64);
    const float mean = s * (1.f / 128.f);
    float s2 = 0.f;
#pragma unroll
    for (int kc = 0; kc < 4; ++kc)
#pragma unroll
        for (int e = 0; e < 8; ++e) { const float d = v[kc][e] - mean; s2 += d * d; }
    s2 += __shfl_xor(s2, 16, 64); s2 += __shfl_xor(s2, 32, 64);
    const float rs = rsqrtf(s2 * (1.f / 128.f) + 1e-5f);
    s16x8 af[4];
#pragma unroll
    for (int kc = 0; kc < 4; ++kc) {
        union { s16x8 v8; unsigned d[4]; } pk;
#pragma unroll
        for (int j = 0; j < 4; ++j) {
            const int col = kc * 32 + 8 * g + 2 * j;
            const float x0 = (v[kc][2 * j] - mean) * rs * gam[col] + bet[col];
            const float x1 = (v[kc][2 * j + 1] - mean) * rs * gam[col + 1] + bet[col + 1];
            pk.d[j] = f2bf2(x0, x1);
        }
        af[kc] = pk.v8;
    }

    f32x4 acc[4];
#pragma unroll
    for (int i = 0; i < 4; ++i) acc[i] = f32x4{0.f, 0.f, 0.f, 0.f};
#pragma unroll
    for (int ns = 0; ns < 4; ++ns) {
        const unsigned short* wrow = Wt + (size_t)(n0 + 16 * ns + c16) * 128;
#pragma unroll
        for (int kc = 0; kc < 4; ++kc) {
            const s16x8 bfv = *(const s16x8*)&wrow[kc * 32 + 8 * g];
            acc[ns] = __builtin_amdgcn_mfma_f32_16x16x32_bf16(
                as_bf16(af[kc]), as_bf16(bfv), acc[ns], 0, 0, 0);
        }
    }
    if (n0 >= 256) {
        const int row0 = m0 + 4 * g;
#pragma unroll
        for (int ns = 0; ns < 4; ++ns) {
            const int n = n0 + ns * 16 + c16;
            const float bv = bias[n];
            u16x4 pk;
#pragma unroll
            for (int r = 0; r < 4; ++r) pk[r] = f2bf(acc[ns][r] + bv);
            *(u16x4*)&vtbuf[(size_t)(n - 256) * 8192 + row0] = pk;
        }
        return;
    }
#pragma unroll
    for (int ns = 0; ns < 4; ++ns) {
        const int n = n0 + ns * 16 + c16;
        const float bv = bias[n];
#pragma unroll
        for (int r = 0; r < 4; ++r)
            qk[(size_t)(m0 + 4 * g + r) * 256 + n] = f2bf(acc[ns][r] + bv);
    }
}

// ---------------------------------------------------------------------------
// Flash v8 (R14-proven): pitch-40 K tiles, KV-split x8 (1024 blocks, 4 KV
// tiles each), bf16 Op partials.  8 waves, role-split staging, LDS dbuf
// KVBLK=128, 32x32x16 mfma, swapped QK^T with involution-permuted K staging
// (QK D-regs == PV A-frags), max-free base-2 softmax, XCD-chunked swizzle.
// ---------------------------------------------------------------------------
__global__ __launch_bounds__(512) void gace_flash8_k(
    const unsigned short* __restrict__ QK,      // [8192][256] q|k, Q pre-scaled
    const unsigned short* __restrict__ Vt,      // [128][8192]
    const unsigned long long* __restrict__ bits,
    unsigned short* __restrict__ Opb, float* __restrict__ ml)
{
    __shared__ __align__(16) unsigned short Ks[2 * 2 * 2560];  // [buf][sub][64 perm][40]
    __shared__ __align__(16) char VtB[2 * 2 * 4096];           // [buf][sub][32 dh][128B swz]

    const int tid = threadIdx.x;
    const int wid = tid >> 6, l = tid & 63;
    const int c32 = l & 31, hi = l >> 5;
    // XCD chunking over 1024 blocks (bijective)
    const int bid = (blockIdx.x & 7) * 128 + (blockIdx.x >> 3);
    const int split = bid & 7, qc = (bid >> 3) & 7, h = (bid >> 6) & 3, b = bid >> 8;
    const size_t base = (size_t)b * 2048;
    const int qb0 = qc * 256 + wid * 32;
    const int q = qb0 + c32;

    const unsigned short* qrow = &QK[(base + q) * 256 + h * 32];
    const s16x8 qf0 = *(const s16x8*)&qrow[8 * hi];
    const s16x8 qf1 = *(const s16x8*)&qrow[16 + 8 * hi];
    const int rot3c = rot3(c32 & 7);

    f32x16 oacc;
#pragma unroll
    for (int i = 0; i < 16; ++i) oacc[i] = 0.f;
    float l_ = 0.f;

    // staging (role-split): tid<256 stages K, tid>=256 stages V
    const int st = tid & 255;
    const int sr = st >> 2;                  // K: kv row 0..63
    const int se = (tid & 3) << 3;           // K: dh elems
    const int lowr = sr & 31, t12 = lowr & 12;
    const int prow = (sr & 32) | (((t12 == 4) | (t12 == 8)) ? (lowr ^ 12) : lowr);
    const int rv = st >> 3;                  // V: dh row 0..31
    const int sv = tid & 7;                  // V: 16B slot
    const int vds = rv * 128 + 16 * (sv ^ rot3(rv & 7));

    const int kv0 = split * 256;
    const unsigned long long* bq = &bits[(base + q) * 32 + split * 4];
    const unsigned short* kgb = &QK[base * 256 + 128 + h * 32 + se];
    const unsigned short* vgb = &Vt[(size_t)(h * 32 + rv) * 8192 + base + kv0 + sv * 8];

    s16x8 kregA, kregB, vregA, vregB;
    auto LOAD = [&](int it2) {
        if (tid < 256) {
            const int kv = kv0 + it2 * 128;
            kregA = *(const s16x8*)&kgb[(size_t)(kv + sr) * 256];
            kregB = *(const s16x8*)&kgb[(size_t)(kv + 64 + sr) * 256];
        } else {
            vregA = *(const s16x8*)&vgb[it2 * 128];
            vregB = *(const s16x8*)&vgb[it2 * 128 + 64];
        }
    };
    auto STAGE = [&](int pb) {
        if (tid < 256) {
            *(s16x8*)&Ks[(pb * 2 + 0) * 2560 + prow * 40 + se] = kregA;
            *(s16x8*)&Ks[(pb * 2 + 1) * 2560 + prow * 40 + se] = kregB;
        } else {
            *(s16x8*)&VtB[(pb * 2 + 0) * 4096 + vds] = vregA;
            *(s16x8*)&VtB[(pb * 2 + 1) * 4096 + vds] = vregB;
        }
    };
    auto COMPUTE = [&](int pb, int sub, unsigned long long wb) {
        const unsigned short* KsS = &Ks[(pb * 2 + sub) * 2560];
        const char* VtS = &VtB[(pb * 2 + sub) * 4096];
        const unsigned long long wbs = wb >> (8 * hi);
        const unsigned wlo = (unsigned)wbs, whiw = (unsigned)(wbs >> 32);
        __builtin_amdgcn_s_setprio(1);
#pragma unroll
        for (int H = 0; H < 2; ++H) {
            const unsigned short* kr = &KsS[(32 * H + c32) * 40 + 8 * hi];
            f32x16 zv;
#pragma unroll
            for (int i = 0; i < 16; ++i) zv[i] = 0.f;
            f32x16 sac = __builtin_amdgcn_mfma_f32_32x32x16_bf16(
                as_bf16(*(const s16x8*)&kr[0]), as_bf16(qf0), zv, 0, 0, 0);
            sac = __builtin_amdgcn_mfma_f32_32x32x16_bf16(
                as_bf16(*(const s16x8*)&kr[16]), as_bf16(qf1), sac, 0, 0, 0);
            const unsigned word = (H == 0) ? wlo : whiw;
#pragma unroll
            for (int ch = 0; ch < 2; ++ch) {
                const int c = 2 * H + ch;
                const int bb = ch * 16;
                float p[8];
#pragma unroll
                for (int e = 0; e < 8; ++e) {
                    const float pe = exp2f(sac[ch * 8 + e]);
                    p[e] = ((word >> (bb + e)) & 1u) ? 0.f : pe;
                }
                l_ += ((p[0] + p[1]) + (p[2] + p[3])) + ((p[4] + p[5]) + (p[6] + p[7]));
                union { s16x8 v; unsigned d[4]; } pa;
#pragma unroll
                for (int j = 0; j < 4; ++j)
                    asm("v_cvt_pk_bf16_f32 %0, %1, %2"
                        : "=v"(pa.d[j]) : "v"(p[2 * j]), "v"(p[2 * j + 1]));
                const s16x8 vf = *(const s16x8*)&VtS[c32 * 128 + 16 * ((2 * c + hi) ^ rot3c)];
                oacc = __builtin_amdgcn_mfma_f32_32x32x16_bf16(
                    as_bf16(pa.v), as_bf16(vf), oacc, 0, 0, 0);
            }
        }
        __builtin_amdgcn_s_setprio(0);
    };

    unsigned long long wbv[4];
#pragma unroll
    for (int w = 0; w < 4; ++w) wbv[w] = bq[w];
    LOAD(0);
    STAGE(0);
    LOAD(1);
    __syncthreads();

#pragma unroll
    for (int it = 0; it < 2; ++it) {
        const int p = it & 1;
        COMPUTE(p, 0, wbv[2 * it]);
        if (it < 1) STAGE(p ^ 1);
        COMPUTE(p, 1, wbv[2 * it + 1]);
        if (it < 1) __syncthreads();
    }

    l_ += __shfl_xor(l_, 32, 64);
    unsigned short* orow = &Opb[((size_t)split * 8192 + base + qb0) * 128 + h * 32 + c32];
#pragma unroll
    for (int r = 0; r < 16; ++r) {
        const int qoff = (r & 3) + 8 * (r >> 2) + 4 * hi;
        orow[(size_t)qoff * 128] = f2bf(oacc[r]);
    }
    if (l < 32) ml[((size_t)split * 8192 + base + q) * 4 + h] = l_;
}

// ---------------------------------------------------------------------------
// Post v2: 512 blocks x 256 thr (4 waves), ONE 16-row tile per block, stages
// n-split across waves through block LDS (xbuf/g1buf) + barriers.
// Combine reads 8 bf16 Op partials.  QKV=1: append layer-1 LN1 + qkv GEMM.
// LAST=1: append post-LN + partials + last-block final output (tailB folded
// in via device-scope atomic counter; output computed by one block in fixed
// order -> bit-deterministic).
// ---------------------------------------------------------------------------
template<int QKV, int LAST>
__global__ __launch_bounds__(256) void gace_post2_k(
    const unsigned short* __restrict__ Opb, const float* __restrict__ ml,
    const unsigned short* __restrict__ oWt, const float* __restrict__ obv,
    float* __restrict__ x,
    const float* __restrict__ n2g, const float* __restrict__ n2b,
    const unsigned short* __restrict__ f1Wt, const float* __restrict__ f1b,
    const unsigned short* __restrict__ f2Wt, const float* __restrict__ f2b,
    const float* __restrict__ n1g2, const float* __restrict__ n1b2,
    const unsigned short* __restrict__ w2, const float* __restrict__ bcat2,
    unsigned short* __restrict__ qk, unsigned short* __restrict__ vtbuf,
    const float* __restrict__ post_g, const float* __restrict__ post_b,
    float* __restrict__ partial,
    const float* __restrict__ lg, const float* __restrict__ outW,
    const float* __restrict__ outb2, float* __restrict__ outp,
    unsigned* __restrict__ cnt)
{
    __shared__ __align__(16) float xbuf[16][132];
    __shared__ __align__(16) unsigned short g1buf[16][264];
    __shared__ float stats[16][2];
    __shared__ unsigned lastv;
    const int tid = threadIdx.x, wid = tid >> 6, l = tid & 63;
    const int g = (l >> 4) & 3, c16 = l & 15;
    const int m0 = blockIdx.x * 16;
    const int arow = m0 + c16;

    // ---- combine 8 KV-splits (bf16 partials) -> o-proj A-frags
    s16x8 af[4];
#pragma unroll
    for (int kc = 0; kc < 4; ++kc) {
        float o[8];
#pragma unroll
        for (int e = 0; e < 8; ++e) o[e] = 0.f;
        float Ls = 0.f;
#pragma unroll
        for (int sp = 0; sp < 8; ++sp) {
            const size_t ro = (size_t)sp * 8192 + arow;
            union { s16x8 v; unsigned short u[8]; } ov;
            ov.v = *(const s16x8*)&Opb[ro * 128 + kc * 32 + 8 * g];
#pragma unroll
            for (int e = 0; e < 8; ++e) o[e] += bf2f(ov.u[e]);
            Ls += ml[ro * 4 + kc];
        }
        const float inv = 1.f / Ls;
        union { s16x8 v8; unsigned d[4]; } pk;
#pragma unroll
        for (int j = 0; j < 4; ++j) pk.d[j] = f2bf2(o[2 * j] * inv, o[2 * j + 1] * inv);
        af[kc] = pk.v8;
    }
    // ---- o-proj: this wave handles ns = 2*wid + {0,1}
    {
        f32x4 acc2[2];
#pragma unroll
        for (int z = 0; z < 2; ++z) acc2[z] = f32x4{0.f, 0.f, 0.f, 0.f};
#pragma unroll
        for (int nsl = 0; nsl < 2; ++nsl) {
            const int ns = wid * 2 + nsl;
            const unsigned short* wrow = oWt + (size_t)(16 * ns + c16) * 128;
#pragma unroll
            for (int kc = 0; kc < 4; ++kc)
                acc2[nsl] = __builtin_amdgcn_mfma_f32_16x16x32_bf16(
                    as_bf16(af[kc]), as_bf16(*(const s16x8*)&wrow[kc * 32 + 8 * g]),
                    acc2[nsl], 0, 0, 0);
        }
#pragma unroll
        for (int nsl = 0; nsl < 2; ++nsl) {
            const int n = 16 * (wid * 2 + nsl) + c16;
            const float bv = obv[n];
#pragma unroll
            for (int r = 0; r < 4; ++r) {
                const int lr = 4 * g + r;
                xbuf[lr][n] = acc2[nsl][r] + bv + x[(size_t)(m0 + lr) * 128 + n];
            }
        }
    }
    __syncthreads();
    // ---- LN2 (redundant per wave from shared xbuf)
    s16x8 af1[4];
    {
        float v2[4][8];
#pragma unroll
        for (int kc = 0; kc < 4; ++kc) {
            const f32x4 a0 = *(const f32x4*)&xbuf[c16][kc * 32 + 8 * g];
            const f32x4 a1 = *(const f32x4*)&xbuf[c16][kc * 32 + 8 * g + 4];
#pragma unroll
            for (int e = 0; e < 4; ++e) { v2[kc][e] = a0[e]; v2[kc][4 + e] = a1[e]; }
        }
        float s = 0.f;
#pragma unroll
        for (int kc = 0; kc < 4; ++kc)
#pragma unroll
            for (int e = 0; e < 8; ++e) s += v2[kc][e];
        s += __shfl_xor(s, 16, 64); s += __shfl_xor(s, 32, 64);
        const float mean = s * (1.f / 128.f);
        float s2 = 0.f;
#pragma unroll
        for (int kc = 0; kc < 4; ++kc)
#pragma unroll
            for (int e = 0; e < 8; ++e) { const float d = v2[kc][e] - mean; s2 += d * d; }
        s2 += __shfl_xor(s2, 16, 64); s2 += __shfl_xor(s2, 32, 64);
        const float rs = rsqrtf(s2 * (1.f / 128.f) + 1e-5f);
#pragma unroll
        for (int kc = 0; kc < 4; ++kc) {
            union { s16x8 v8; unsigned d[4]; } pk;
#pragma unroll
            for (int j = 0; j < 4; ++j) {
                const int col = kc * 32 + 8 * g + 2 * j;
                const float x0 = (v2[kc][2 * j] - mean) * rs * n2g[col] + n2b[col];
                const float x1 = (v2[kc][2 * j + 1] - mean) * rs * n2g[col + 1] + n2b[col + 1];
                pk.d[j] = f2bf2(x0, x1);
            }
            af1[kc] = pk.v8;
        }
    }
    // ---- FF1 + GELU: ns = 4*wid + {0..3}
    {
        f32x4 accf[4];
#pragma unroll
        for (int z = 0; z < 4; ++z) accf[z] = f32x4{0.f, 0.f, 0.f, 0.f};
#pragma unroll
        for (int nsl = 0; nsl < 4; ++nsl) {
            const int ns = wid * 4 + nsl;
            const unsigned short* wrow = f1Wt + (size_t)(16 * ns + c16) * 128;
#pragma unroll
            for (int kc = 0; kc < 4; ++kc)
                accf[nsl] = __builtin_amdgcn_mfma_f32_16x16x32_bf16(
                    as_bf16(af1[kc]), as_bf16(*(const s16x8*)&wrow[kc * 32 + 8 * g]),
                    accf[nsl], 0, 0, 0);
        }
#pragma unroll
        for (int nsl = 0; nsl < 4; ++nsl) {
            const int n = 16 * (wid * 4 + nsl) + c16;
            const float bv = f1b[n];
#pragma unroll
            for (int r = 0; r < 4; ++r) {
                float vv = accf[nsl][r] + bv;
                vv = vv * 0.5f * (1.0f + erff(vv * 0.70710678118654752f));
                g1buf[4 * g + r][n] = f2bf(vv);
            }
        }
    }
    __syncthreads();
    // ---- FF2: ns = 2*wid + {0,1}, full K=256 from shared g1buf
    float fx[2][4];
    {
        s16x8 af2[8];
#pragma unroll
        for (int kc = 0; kc < 8; ++kc)
            af2[kc] = *(const s16x8*)&g1buf[c16][kc * 32 + 8 * g];
        f32x4 acc2[2];
#pragma unroll
        for (int z = 0; z < 2; ++z) acc2[z] = f32x4{0.f, 0.f, 0.f, 0.f};
#pragma unroll
        for (int nsl = 0; nsl < 2; ++nsl) {
            const int ns = wid * 2 + nsl;
            const unsigned short* wrow = f2Wt + (size_t)(16 * ns + c16) * 256;
#pragma unroll
            for (int kc = 0; kc < 8; ++kc)
                acc2[nsl] = __builtin_amdgcn_mfma_f32_16x16x32_bf16(
                    as_bf16(af2[kc]), as_bf16(*(const s16x8*)&wrow[kc * 32 + 8 * g]),
                    acc2[nsl], 0, 0, 0);
        }
#pragma unroll
        for (int nsl = 0; nsl < 2; ++nsl) {
            const int n = 16 * (wid * 2 + nsl) + c16;
            const float bv = f2b[n];
#pragma unroll
            for (int r = 0; r < 4; ++r)
                fx[nsl][r] = acc2[nsl][r] + bv + xbuf[4 * g + r][n];
        }
    }
    if (!QKV && !LAST) {
#pragma unroll
        for (int nsl = 0; nsl < 2; ++nsl) {
            const int n = 16 * (wid * 2 + nsl) + c16;
#pragma unroll
            for (int r = 0; r < 4; ++r)
                x[(size_t)(m0 + 4 * g + r) * 128 + n] = fx[nsl][r];
        }
        return;
    }
    // write fx into xbuf (own cols only; disjoint across waves)
#pragma unroll
    for (int nsl = 0; nsl < 2; ++nsl) {
        const int n = 16 * (wid * 2 + nsl) + c16;
#pragma unroll
        for (int r = 0; r < 4; ++r) {
            const int lr = 4 * g + r;
            if (QKV) x[(size_t)(m0 + lr) * 128 + n] = fx[nsl][r];
            xbuf[lr][n] = fx[nsl][r];
        }
    }
    __syncthreads();
    if (QKV) {
        // ---- fused layer-1 LN1 (redundant per wave) -> A-frags
        s16x8 afq[4];
        {
            float v1[4][8];
#pragma unroll
            for (int kc = 0; kc < 4; ++kc) {
                const f32x4 a0 = *(const f32x4*)&xbuf[c16][kc * 32 + 8 * g];
                const f32x4 a1 = *(const f32x4*)&xbuf[c16][kc * 32 + 8 * g + 4];
#pragma unroll
                for (int e = 0; e < 4; ++e) { v1[kc][e] = a0[e]; v1[kc][4 + e] = a1[e]; }
            }
            float s1 = 0.f;
#pragma unroll
            for (int kc = 0; kc < 4; ++kc)
#pragma unroll
                for (int e = 0; e < 8; ++e) s1 += v1[kc][e];
            s1 += __shfl_xor(s1, 16, 64); s1 += __shfl_xor(s1, 32, 64);
            const float mean1 = s1 * (1.f / 128.f);
            float sq1 = 0.f;
#pragma unroll
            for (int kc = 0; kc < 4; ++kc)
#pragma unroll
                for (int e = 0; e < 8; ++e) { const float d = v1[kc][e] - mean1; sq1 += d * d; }
            sq1 += __shfl_xor(sq1, 16, 64); sq1 += __shfl_xor(sq1, 32, 64);
            const float rs1 = rsqrtf(sq1 * (1.f / 128.f) + 1e-5f);
#pragma unroll
            for (int kc = 0; kc < 4; ++kc) {
                union { s16x8 v8; unsigned d[4]; } pk;
#pragma unroll
                for (int j = 0; j < 4; ++j) {
                    const int col = kc * 32 + 8 * g + 2 * j;
                    const float x0 = (v1[kc][2 * j] - mean1) * rs1 * n1g2[col] + n1b2[col];
                    const float x1 = (v1[kc][2 * j + 1] - mean1) * rs1 * n1g2[col + 1] + n1b2[col + 1];
                    pk.d[j] = f2bf2(x0, x1);
                }
                afq[kc] = pk.v8;
            }
        }
        // ---- layer-1 qkv: 24 ns, 6 per wave
#pragma unroll
        for (int j = 0; j < 6; ++j) {
            const int ns = wid * 6 + j;
            const unsigned short* wrow = w2 + (size_t)(ns * 16 + c16) * 128;
            f32x4 acc = f32x4{0.f, 0.f, 0.f, 0.f};
#pragma unroll
            for (int kc = 0; kc < 4; ++kc)
                acc = __builtin_amdgcn_mfma_f32_16x16x32_bf16(
                    as_bf16(afq[kc]), as_bf16(*(const s16x8*)&wrow[kc * 32 + 8 * g]),
                    acc, 0, 0, 0);
            const int n = ns * 16 + c16;
            const float bv = bcat2[n];
            if (ns >= 16) {
                const int row0 = m0 + 4 * g;
                u16x4 pk;
#pragma unroll
                for (int r = 0; r < 4; ++r) pk[r] = f2bf(acc[r] + bv);
                *(u16x4*)&vtbuf[(size_t)(n - 256) * 8192 + row0] = pk;
            } else {
#pragma unroll
                for (int r = 0; r < 4; ++r)
                    qk[(size_t)(m0 + 4 * g + r) * 256 + n] = f2bf(acc[r] + bv);
            }
        }
        return;
    }
    // ---- LAST: cooperative row stats (4 rows/wave) then disjoint col partials
    if (LAST) {
#pragma unroll
        for (int rr = 0; rr < 4; ++rr) {
            const int row = wid * 4 + rr;
            const float v0 = xbuf[row][l], v1 = xbuf[row][l + 64];
            const float s = wave_sum64(v0 + v1);
            const float mean = s * (1.f / 128.f);
            const float d0 = v0 - mean, d1 = v1 - mean;
            const float s2 = wave_sum64(d0 * d0 + d1 * d1);
            const float rstd = rsqrtf(s2 * (1.f / 128.f) + 1e-5f);
            if (l == 0) { stats[row][0] = mean; stats[row][1] = rstd; }
        }
        __syncthreads();
#pragma unroll
        for (int nsl = 0; nsl < 2; ++nsl) {
            const int ns = wid * 2 + nsl;
            const int n = 16 * ns + c16;
            const float pg = post_g[n], pb_ = post_b[n];
            float cs = 0.f;
#pragma unroll
            for (int r = 0; r < 4; ++r) {
                const int row = 4 * g + r;
                cs += (xbuf[row][n] - stats[row][0]) * stats[row][1] * pg + pb_;
            }
            cs += __shfl_xor(cs, 16, 64);
            cs += __shfl_xor(cs, 32, 64);
            if (l < 16) partial[(size_t)blockIdx.x * 128 + n] = cs;
        }
        // ---- last-block tail: fused = mean + 0.1*lg; out = fused@out_W+out_b
        __threadfence();
        __syncthreads();
        if (tid == 0) lastv = atomicAdd(cnt, 1u);
        __syncthreads();
        if (lastv == 511u) {
            __threadfence();
            float* fusedL = (float*)xbuf;        // 512 floats, reuse LDS
#pragma unroll
            for (int it = 0; it < 2; ++it) {
                const int p = it * 256 + tid;
                const int b2 = p >> 7, col = p & 127;
                float s = 0.f;
                for (int c = 0; c < 128; ++c)
                    s += partial[(size_t)(b2 * 128 + c) * 128 + col];
                fusedL[p] = s * (1.f / 2048.f) + 0.1f * lg[p];
            }
            __syncthreads();
#pragma unroll
            for (int it = 0; it < 2; ++it) {
                const int p = it * 256 + tid;
                const int b2 = p >> 7, col = p & 127;
                float r = outb2[col];
                for (int d = 0; d < 128; ++d)
                    r += fusedL[b2 * 128 + d] * outW[d * 128 + col];
                outp[p] = r;
            }
        }
    }
}

// ---------------------------------------------------------------------------
extern "C" void kernel_launch(void* const* d_in, const int* in_sizes, int n_in,
                              void* d_out, int out_size, void* d_ws, size_t ws_size,
                              hipStream_t stream)
{
    (void)in_sizes; (void)n_in; (void)out_size; (void)ws_size;
    const float* local_global = (const float*)d_in[0];
    const float* task   = (const float*)d_in[1];
    const float* priv   = (const float*)d_in[2];
    const float* dag    = (const float*)d_in[3];
    const float* amask  = (const float*)d_in[4];
    const float* task_W = (const float*)d_in[5];
    const float* task_b = (const float*)d_in[6];
    const float* priv_W = (const float*)d_in[7];
    const float* priv_b = (const float*)d_in[8];
    const float* dag_W  = (const float*)d_in[9];
    const float* dag_b  = (const float*)d_in[10];
    const float* pre_g  = (const float*)d_in[11];
    const float* pre_b  = (const float*)d_in[12];
    const float* post_g = (const float*)d_in[13];
    const float* post_b = (const float*)d_in[14];
    const float* out_W  = (const float*)d_in[15];
    const float* out_b  = (const float*)d_in[16];
    const float* qW = (const float*)d_in[17];
    const float* qb = (const float*)d_in[18];
    const float* kW = (const float*)d_in[19];
    const float* kb = (const float*)d_in[20];
    const float* vW = (const float*)d_in[21];
    const float* vb = (const float*)d_in[22];
    const float* oW = (const float*)d_in[23];
    const float* ob = (const float*)d_in[24];
    const float* n1g = (const float*)d_in[25];
    const float* n1b = (const float*)d_in[26];
    const float* n2g = (const float*)d_in[27];
    const float* n2b = (const float*)d_in[28];
    const float* f1W = (const float*)d_in[29];
    const float* f1b = (const float*)d_in[30];
    const float* f2W = (const float*)d_in[31];
    const float* f2b = (const float*)d_in[32];

    char* ws = (char*)d_ws;
    size_t off = 0;
    auto carve = [&](size_t sz) {
        void* p = ws + off;
        off += (sz + 255) & ~(size_t)255;
        return p;
    };
    unsigned long long* bits = (unsigned long long*)carve(8192ull * 32 * 8);  // 2 MB
    float*          x    = (float*)carve(8192ull * 128 * 4);                   // 4 MB
    unsigned short* qk   = (unsigned short*)carve(8192ull * 256 * 2);          // 4 MB (q|k)
    unsigned short* vt   = (unsigned short*)carve(128ull * 8192 * 2);          // 2 MB (V^T)
    float*          part = (float*)carve(512ull * 128 * 4);                    // 256 KB
    unsigned short* Opb  = (unsigned short*)carve(8ull * 8192 * 128 * 2);      // 16 MB
    float*          mlb  = (float*)carve(8ull * 8192 * 4 * 4);                 // 1 MB
    unsigned short* wbf  = (unsigned short*)carve(2ull * 131072 * 2);          // 512 KB
    float*          bcat = (float*)carve(2ull * 384 * 4);
    unsigned*       cnt  = (unsigned*)carve(256);

    gace_setup_k<<<4353, 256, 0, stream>>>(
        amask, bits,
        task, priv, dag, task_W, task_b, priv_W, priv_b, dag_W, dag_b,
        pre_g, pre_b, x,
        qW, kW, vW, oW, f1W, f2W, qb, kb, vb, wbf, bcat, cnt);
    // layer 0
    gace_qkv_k<<<dim3(128, 6), 256, 0, stream>>>(
        x, n1g, n1b, wbf, bcat, qk, vt);
    gace_flash8_k<<<1024, 512, 0, stream>>>(qk, vt, bits, Opb, mlb);
    // post(layer 0) fused with qkv(layer 1) — 4-wave n-split blocks
    gace_post2_k<1, 0><<<512, 256, 0, stream>>>(
        Opb, mlb, wbf + 49152, ob, x, n2g, n2b,
        wbf + 65536, f1b, wbf + 98304, f2b,
        n1g + 128, n1b + 128, wbf + 131072, bcat + 384, qk, vt,
        nullptr, nullptr, nullptr,
        nullptr, nullptr, nullptr, nullptr, nullptr);
    // layer 1
    gace_flash8_k<<<1024, 512, 0, stream>>>(qk, vt, bits, Opb, mlb);
    // post(layer 1) with folded tail (last-block pattern)
    gace_post2_k<0, 1><<<512, 256, 0, stream>>>(
        Opb, mlb, wbf + 131072 + 49152, ob + 128, x, n2g + 128, n2b + 128,
        wbf + 131072 + 65536, f1b + 256, wbf + 131072 + 98304, f2b + 128,
        nullptr, nullptr, nullptr, nullptr, nullptr, nullptr,
        post_g, post_b, part,
        local_global, out_W, out_b, (float*)d_out, cnt);
}

// Round 16
// 157.352 us; speedup vs baseline: 1.2211x; 1.2211x over previous
//
#include <hip/hip_runtime.h>
#include <hip/hip_bf16.h>

#define DEV __device__ __forceinline__

typedef float f32x4 __attribute__((ext_vector_type(4)));
typedef float f32x16 __attribute__((ext_vector_type(16)));
typedef short s16x8 __attribute__((ext_vector_type(8)));
typedef unsigned short u16x4 __attribute__((ext_vector_type(4)));
typedef __bf16 bf16x8 __attribute__((ext_vector_type(8)));

DEV bf16x8 as_bf16(s16x8 v) { return __builtin_bit_cast(bf16x8, v); }

DEV unsigned short f2bf(float f) {
    union { __hip_bfloat16 h; unsigned short u; } c;
    c.h = __float2bfloat16(f);
    return c.u;
}

DEV float bf2f(unsigned short u) {
    return __builtin_bit_cast(float, (unsigned)u << 16);
}

// RNE f32->bf16 pair pack (finite inputs only)
DEV unsigned f2bf2(float lo, float hi) {
    unsigned ulo = __builtin_bit_cast(unsigned, lo);
    unsigned uhi = __builtin_bit_cast(unsigned, hi);
    ulo = (ulo + 0x7fffu + ((ulo >> 16) & 1u)) >> 16;
    uhi = (uhi + 0x7fffu + ((uhi >> 16) & 1u)) & 0xffff0000u;
    return ulo | uhi;
}

DEV float wave_sum64(float v) {
#pragma unroll
    for (int m = 1; m < 64; m <<= 1) v += __shfl_xor(v, m, 64);
    return v;
}

// 3-bit rotate-left; 16B-slot swizzle
DEV int rot3(int r) { return ((r << 1) | (r >> 2)) & 7; }

constexpr float QSCL = (float)(1.4426950408889634 / 5.656854249492381);  // log2(e)/sqrt(32)

// ---------------------------------------------------------------------------
// Setup (merged): [0,2048) mask -> bits; [2048,4096) ctx+preLN -> x;
// [4096,4352) weight prep via coalesced 32x32 LDS tile transpose;
// bx==4352: bias concat
// ---------------------------------------------------------------------------
__global__ __launch_bounds__(256) void gace_setup_k(
    const float* __restrict__ am, unsigned long long* __restrict__ bits,
    const float* __restrict__ task, const float* __restrict__ priv, const float* __restrict__ dag,
    const float* __restrict__ tW, const float* __restrict__ tb,
    const float* __restrict__ pW, const float* __restrict__ pb,
    const float* __restrict__ dW, const float* __restrict__ db,
    const float* __restrict__ pre_g, const float* __restrict__ pre_b,
    float* __restrict__ x,
    const float* __restrict__ qW, const float* __restrict__ kW,
    const float* __restrict__ vW, const float* __restrict__ oW,
    const float* __restrict__ f1W, const float* __restrict__ f2W,
    const float* __restrict__ qb, const float* __restrict__ kb,
    const float* __restrict__ vb,
    unsigned short* __restrict__ wbf, float* __restrict__ bcat)
{
    __shared__ unsigned short tileS[32][33];
    const int bx = blockIdx.x;
    const int tid = threadIdx.x, wid = tid >> 6, l = tid & 63;
    if (bx < 2048) {
        // mask quirks: no-masked row -> set diag (need_fix); all-masked row ->
        // clear diag (== torch diag-score-0 fixup in softmax-weight space)
        const int row = bx * 4 + wid;
        const float* mrow = am + (size_t)row * 2048;
        unsigned long long myword = 0, orAll = 0, andAll = ~0ull;
#pragma unroll 4
        for (int w = 0; w < 32; ++w) {
            unsigned long long bal = __ballot(mrow[w * 64 + l] > 0.5f);
            if (w == l) myword = bal;
            orAll |= bal; andAll &= bal;
        }
        const int lrow = row & 2047;
        const int dw = lrow >> 6, dbit = lrow & 63;
        if (l == dw) {
            if (orAll == 0ull) myword |= (1ull << dbit);
            else if (andAll == ~0ull) myword &= ~(1ull << dbit);
        }
        if (l < 32) bits[(size_t)row * 32 + l] = myword;
        return;
    }
    if (bx < 4096) {
        const int row = (bx - 2048) * 4 + wid;
        const int d0 = l, d1 = l + 64;
        float a0 = tb[d0] + pb[d0] + db[d0];
        float a1 = tb[d1] + pb[d1] + db[d1];
        const float* tf = task + (size_t)row * 15;
#pragma unroll
        for (int j = 0; j < 15; ++j) { const float t = tf[j]; a0 += t * tW[j * 128 + d0]; a1 += t * tW[j * 128 + d1]; }
        const float* pf = priv + (size_t)row * 6;
#pragma unroll
        for (int j = 0; j < 6; ++j) { const float t = pf[j]; a0 += t * pW[j * 128 + d0]; a1 += t * pW[j * 128 + d1]; }
        const float* df = dag + (size_t)row * 4;
#pragma unroll
        for (int j = 0; j < 4; ++j) { const float t = df[j]; a0 += t * dW[j * 128 + d0]; a1 += t * dW[j * 128 + d1]; }
        const float s = wave_sum64(a0 + a1);
        const float mean = s * (1.f / 128.f);
        const float e0 = a0 - mean, e1 = a1 - mean;
        const float s2 = wave_sum64(e0 * e0 + e1 * e1);
        const float rs = rsqrtf(s2 * (1.f / 128.f) + 1e-5f);
        x[(size_t)row * 128 + d0] = e0 * rs * pre_g[d0] + pre_b[d0];
        x[(size_t)row * 128 + d1] = e1 * rs * pre_g[d1] + pre_b[d1];
        return;
    }
    if (bx < 4352) {
        // ---- weight prep: one 32x32 tile per block, coalesced both sides
        const int t = bx - 4096;                  // 0..255
        const int i = t >> 7, tl = t & 127;
        const float* src; int K_, N_, off, kt, nt; float scl = 1.0f;
        if (tl < 64) {
            const int y = tl >> 4, sub = tl & 15;
            kt = sub >> 2; nt = sub & 3;
            K_ = 128; N_ = 128;
            switch (y) {
                case 0:  src = qW; off = 0;     scl = QSCL; break;
                case 1:  src = kW; off = 16384; break;
                case 2:  src = vW; off = 32768; break;
                default: src = oW; off = 49152; break;
            }
        } else if (tl < 96) {
            const int sub = tl - 64; kt = sub >> 3; nt = sub & 7;
            K_ = 128; N_ = 256; src = f1W; off = 65536;
        } else {
            const int sub = tl - 96; kt = sub >> 2; nt = sub & 3;
            K_ = 256; N_ = 128; src = f2W; off = 98304;
        }
        const int per = K_ * N_;
        const int k0 = kt * 32, n0 = nt * 32;
        const int rr = tid >> 5, cc = tid & 31;
#pragma unroll
        for (int it = 0; it < 4; ++it) {
            const int r = it * 8 + rr;
            tileS[r][cc] = f2bf(src[(size_t)i * per + (size_t)(k0 + r) * N_ + n0 + cc] * scl);
        }
        __syncthreads();
#pragma unroll
        for (int it = 0; it < 4; ++it) {
            const int n = it * 8 + rr;
            wbf[(size_t)i * 131072 + off + (size_t)(n0 + n) * K_ + k0 + cc] = tileS[cc][n];
        }
        return;
    }
    // ---- bias concat
    for (int j = tid; j < 768; j += 256) {
        const int i = j / 384, jj = j % 384;
        float v;
        if (jj < 128)      v = qb[i * 128 + jj] * QSCL;
        else if (jj < 256) v = kb[i * 128 + jj - 128];
        else               v = vb[i * 128 + jj - 256];
        bcat[j] = v;
    }
}

// ---------------------------------------------------------------------------
// qkv GEMM with fused LN1, no LDS.  V cols (n>=256) stored transposed.
// (layer 0 only; layer 1's qkv is fused into gace_post2_k<1,0>)
// ---------------------------------------------------------------------------
__global__ __launch_bounds__(256) void gace_qkv_k(
    const float* __restrict__ xin,
    const float* __restrict__ gam, const float* __restrict__ bet,
    const unsigned short* __restrict__ Wt,
    const float* __restrict__ bias,
    unsigned short* __restrict__ qk, unsigned short* __restrict__ vtbuf)
{
    const int tid = threadIdx.x;
    const int wid = tid >> 6, l = tid & 63;
    const int g = (l >> 4) & 3, c16 = l & 15;
    const int m0 = blockIdx.x * 64 + wid * 16;
    const int n0 = blockIdx.y * 64;
    const int arow = m0 + c16;

    float v[4][8];
#pragma unroll
    for (int kc = 0; kc < 4; ++kc) {
        const f32x4 a0 = *(const f32x4*)&xin[(size_t)arow * 128 + kc * 32 + 8 * g];
        const f32x4 a1 = *(const f32x4*)&xin[(size_t)arow * 128 + kc * 32 + 8 * g + 4];
#pragma unroll
        for (int e = 0; e < 4; ++e) { v[kc][e] = a0[e]; v[kc][4 + e] = a1[e]; }
    }
    float s = 0.f;
#pragma unroll
    for (int kc = 0; kc < 4; ++kc)
#pragma unroll
        for (int e = 0; e < 8; ++e) s += v[kc][e];
    s += __shfl_xor(s, 16, 64); s += __shfl_xor(s, 32, 64);
    const float mean = s * (1.f / 128.f);
    float s2 = 0.f;
#pragma unroll
    for (int kc = 0; kc < 4; ++kc)
#pragma unroll
        for (int e = 0; e < 8; ++e) { const float d = v[kc][e] - mean; s2 += d * d; }
    s2 += __shfl_xor(s2, 16, 64); s2 += __shfl_xor(s2, 32, 64);
    const float rs = rsqrtf(s2 * (1.f / 128.f) + 1e-5f);
    s16x8 af[4];
#pragma unroll
    for (int kc = 0; kc < 4; ++kc) {
        union { s16x8 v8; unsigned d[4]; } pk;
#pragma unroll
        for (int j = 0; j < 4; ++j) {
            const int col = kc * 32 + 8 * g + 2 * j;
            const float x0 = (v[kc][2 * j] - mean) * rs * gam[col] + bet[col];
            const float x1 = (v[kc][2 * j + 1] - mean) * rs * gam[col + 1] + bet[col + 1];
            pk.d[j] = f2bf2(x0, x1);
        }
        af[kc] = pk.v8;
    }

    f32x4 acc[4];
#pragma unroll
    for (int i = 0; i < 4; ++i) acc[i] = f32x4{0.f, 0.f, 0.f, 0.f};
#pragma unroll
    for (int ns = 0; ns < 4; ++ns) {
        const unsigned short* wrow = Wt + (size_t)(n0 + 16 * ns + c16) * 128;
#pragma unroll
        for (int kc = 0; kc < 4; ++kc) {
            const s16x8 bfv = *(const s16x8*)&wrow[kc * 32 + 8 * g];
            acc[ns] = __builtin_amdgcn_mfma_f32_16x16x32_bf16(
                as_bf16(af[kc]), as_bf16(bfv), acc[ns], 0, 0, 0);
        }
    }
    if (n0 >= 256) {
        const int row0 = m0 + 4 * g;
#pragma unroll
        for (int ns = 0; ns < 4; ++ns) {
            const int n = n0 + ns * 16 + c16;
            const float bv = bias[n];
            u16x4 pk;
#pragma unroll
            for (int r = 0; r < 4; ++r) pk[r] = f2bf(acc[ns][r] + bv);
            *(u16x4*)&vtbuf[(size_t)(n - 256) * 8192 + row0] = pk;
        }
        return;
    }
#pragma unroll
    for (int ns = 0; ns < 4; ++ns) {
        const int n = n0 + ns * 16 + c16;
        const float bv = bias[n];
#pragma unroll
        for (int r = 0; r < 4; ++r)
            qk[(size_t)(m0 + 4 * g + r) * 256 + n] = f2bf(acc[ns][r] + bv);
    }
}

// ---------------------------------------------------------------------------
// Flash v8 (R14-proven): pitch-40 K tiles, KV-split x8 (1024 blocks, 4 KV
// tiles each), bf16 Op partials.  8 waves, role-split staging, LDS dbuf
// KVBLK=128, 32x32x16 mfma, swapped QK^T with involution-permuted K staging
// (QK D-regs == PV A-frags), max-free base-2 softmax, XCD-chunked swizzle.
// ---------------------------------------------------------------------------
__global__ __launch_bounds__(512) void gace_flash8_k(
    const unsigned short* __restrict__ QK,      // [8192][256] q|k, Q pre-scaled
    const unsigned short* __restrict__ Vt,      // [128][8192]
    const unsigned long long* __restrict__ bits,
    unsigned short* __restrict__ Opb, float* __restrict__ ml)
{
    __shared__ __align__(16) unsigned short Ks[2 * 2 * 2560];  // [buf][sub][64 perm][40]
    __shared__ __align__(16) char VtB[2 * 2 * 4096];           // [buf][sub][32 dh][128B swz]

    const int tid = threadIdx.x;
    const int wid = tid >> 6, l = tid & 63;
    const int c32 = l & 31, hi = l >> 5;
    // XCD chunking over 1024 blocks (bijective)
    const int bid = (blockIdx.x & 7) * 128 + (blockIdx.x >> 3);
    const int split = bid & 7, qc = (bid >> 3) & 7, h = (bid >> 6) & 3, b = bid >> 8;
    const size_t base = (size_t)b * 2048;
    const int qb0 = qc * 256 + wid * 32;
    const int q = qb0 + c32;

    const unsigned short* qrow = &QK[(base + q) * 256 + h * 32];
    const s16x8 qf0 = *(const s16x8*)&qrow[8 * hi];
    const s16x8 qf1 = *(const s16x8*)&qrow[16 + 8 * hi];
    const int rot3c = rot3(c32 & 7);

    f32x16 oacc;
#pragma unroll
    for (int i = 0; i < 16; ++i) oacc[i] = 0.f;
    float l_ = 0.f;

    // staging (role-split): tid<256 stages K, tid>=256 stages V
    const int st = tid & 255;
    const int sr = st >> 2;                  // K: kv row 0..63
    const int se = (tid & 3) << 3;           // K: dh elems
    const int lowr = sr & 31, t12 = lowr & 12;
    const int prow = (sr & 32) | (((t12 == 4) | (t12 == 8)) ? (lowr ^ 12) : lowr);
    const int rv = st >> 3;                  // V: dh row 0..31
    const int sv = tid & 7;                  // V: 16B slot
    const int vds = rv * 128 + 16 * (sv ^ rot3(rv & 7));

    const int kv0 = split * 256;
    const unsigned long long* bq = &bits[(base + q) * 32 + split * 4];
    const unsigned short* kgb = &QK[base * 256 + 128 + h * 32 + se];
    const unsigned short* vgb = &Vt[(size_t)(h * 32 + rv) * 8192 + base + kv0 + sv * 8];

    s16x8 kregA, kregB, vregA, vregB;
    auto LOAD = [&](int it2) {
        if (tid < 256) {
            const int kv = kv0 + it2 * 128;
            kregA = *(const s16x8*)&kgb[(size_t)(kv + sr) * 256];
            kregB = *(const s16x8*)&kgb[(size_t)(kv + 64 + sr) * 256];
        } else {
            vregA = *(const s16x8*)&vgb[it2 * 128];
            vregB = *(const s16x8*)&vgb[it2 * 128 + 64];
        }
    };
    auto STAGE = [&](int pb) {
        if (tid < 256) {
            *(s16x8*)&Ks[(pb * 2 + 0) * 2560 + prow * 40 + se] = kregA;
            *(s16x8*)&Ks[(pb * 2 + 1) * 2560 + prow * 40 + se] = kregB;
        } else {
            *(s16x8*)&VtB[(pb * 2 + 0) * 4096 + vds] = vregA;
            *(s16x8*)&VtB[(pb * 2 + 1) * 4096 + vds] = vregB;
        }
    };
    auto COMPUTE = [&](int pb, int sub, unsigned long long wb) {
        const unsigned short* KsS = &Ks[(pb * 2 + sub) * 2560];
        const char* VtS = &VtB[(pb * 2 + sub) * 4096];
        const unsigned long long wbs = wb >> (8 * hi);
        const unsigned wlo = (unsigned)wbs, whiw = (unsigned)(wbs >> 32);
        __builtin_amdgcn_s_setprio(1);
#pragma unroll
        for (int H = 0; H < 2; ++H) {
            const unsigned short* kr = &KsS[(32 * H + c32) * 40 + 8 * hi];
            f32x16 zv;
#pragma unroll
            for (int i = 0; i < 16; ++i) zv[i] = 0.f;
            f32x16 sac = __builtin_amdgcn_mfma_f32_32x32x16_bf16(
                as_bf16(*(const s16x8*)&kr[0]), as_bf16(qf0), zv, 0, 0, 0);
            sac = __builtin_amdgcn_mfma_f32_32x32x16_bf16(
                as_bf16(*(const s16x8*)&kr[16]), as_bf16(qf1), sac, 0, 0, 0);
            const unsigned word = (H == 0) ? wlo : whiw;
#pragma unroll
            for (int ch = 0; ch < 2; ++ch) {
                const int c = 2 * H + ch;
                const int bb = ch * 16;
                float p[8];
#pragma unroll
                for (int e = 0; e < 8; ++e) {
                    const float pe = exp2f(sac[ch * 8 + e]);
                    p[e] = ((word >> (bb + e)) & 1u) ? 0.f : pe;
                }
                l_ += ((p[0] + p[1]) + (p[2] + p[3])) + ((p[4] + p[5]) + (p[6] + p[7]));
                union { s16x8 v; unsigned d[4]; } pa;
#pragma unroll
                for (int j = 0; j < 4; ++j)
                    asm("v_cvt_pk_bf16_f32 %0, %1, %2"
                        : "=v"(pa.d[j]) : "v"(p[2 * j]), "v"(p[2 * j + 1]));
                const s16x8 vf = *(const s16x8*)&VtS[c32 * 128 + 16 * ((2 * c + hi) ^ rot3c)];
                oacc = __builtin_amdgcn_mfma_f32_32x32x16_bf16(
                    as_bf16(pa.v), as_bf16(vf), oacc, 0, 0, 0);
            }
        }
        __builtin_amdgcn_s_setprio(0);
    };

    unsigned long long wbv[4];
#pragma unroll
    for (int w = 0; w < 4; ++w) wbv[w] = bq[w];
    LOAD(0);
    STAGE(0);
    LOAD(1);
    __syncthreads();

#pragma unroll
    for (int it = 0; it < 2; ++it) {
        const int p = it & 1;
        COMPUTE(p, 0, wbv[2 * it]);
        if (it < 1) STAGE(p ^ 1);
        COMPUTE(p, 1, wbv[2 * it + 1]);
        if (it < 1) __syncthreads();
    }

    l_ += __shfl_xor(l_, 32, 64);
    unsigned short* orow = &Opb[((size_t)split * 8192 + base + qb0) * 128 + h * 32 + c32];
#pragma unroll
    for (int r = 0; r < 16; ++r) {
        const int qoff = (r & 3) + 8 * (r >> 2) + 4 * hi;
        orow[(size_t)qoff * 128] = f2bf(oacc[r]);
    }
    if (l < 32) ml[((size_t)split * 8192 + base + q) * 4 + h] = l_;
}

// ---------------------------------------------------------------------------
// Post v2 (R14-proven): 512 blocks x 256 thr (4 waves), ONE 16-row tile per
// block, stages n-split across waves through block LDS + barriers.
// Combine reads 8 bf16 Op partials.  QKV=1: append layer-1 LN1 + qkv GEMM.
// LAST=1: append post-LN (cooperative row stats) + column partial sums.
// ---------------------------------------------------------------------------
template<int QKV, int LAST>
__global__ __launch_bounds__(256) void gace_post2_k(
    const unsigned short* __restrict__ Opb, const float* __restrict__ ml,
    const unsigned short* __restrict__ oWt, const float* __restrict__ obv,
    float* __restrict__ x,
    const float* __restrict__ n2g, const float* __restrict__ n2b,
    const unsigned short* __restrict__ f1Wt, const float* __restrict__ f1b,
    const unsigned short* __restrict__ f2Wt, const float* __restrict__ f2b,
    const float* __restrict__ n1g2, const float* __restrict__ n1b2,
    const unsigned short* __restrict__ w2, const float* __restrict__ bcat2,
    unsigned short* __restrict__ qk, unsigned short* __restrict__ vtbuf,
    const float* __restrict__ post_g, const float* __restrict__ post_b,
    float* __restrict__ partial)
{
    __shared__ __align__(16) float xbuf[16][132];
    __shared__ __align__(16) unsigned short g1buf[16][264];
    __shared__ float stats[16][2];
    const int tid = threadIdx.x, wid = tid >> 6, l = tid & 63;
    const int g = (l >> 4) & 3, c16 = l & 15;
    const int m0 = blockIdx.x * 16;
    const int arow = m0 + c16;

    // ---- combine 8 KV-splits (bf16 partials) -> o-proj A-frags
    s16x8 af[4];
#pragma unroll
    for (int kc = 0; kc < 4; ++kc) {
        float o[8];
#pragma unroll
        for (int e = 0; e < 8; ++e) o[e] = 0.f;
        float Ls = 0.f;
#pragma unroll
        for (int sp = 0; sp < 8; ++sp) {
            const size_t ro = (size_t)sp * 8192 + arow;
            union { s16x8 v; unsigned short u[8]; } ov;
            ov.v = *(const s16x8*)&Opb[ro * 128 + kc * 32 + 8 * g];
#pragma unroll
            for (int e = 0; e < 8; ++e) o[e] += bf2f(ov.u[e]);
            Ls += ml[ro * 4 + kc];
        }
        const float inv = 1.f / Ls;
        union { s16x8 v8; unsigned d[4]; } pk;
#pragma unroll
        for (int j = 0; j < 4; ++j) pk.d[j] = f2bf2(o[2 * j] * inv, o[2 * j + 1] * inv);
        af[kc] = pk.v8;
    }
    // ---- o-proj: this wave handles ns = 2*wid + {0,1}
    {
        f32x4 acc2[2];
#pragma unroll
        for (int z = 0; z < 2; ++z) acc2[z] = f32x4{0.f, 0.f, 0.f, 0.f};
#pragma unroll
        for (int nsl = 0; nsl < 2; ++nsl) {
            const int ns = wid * 2 + nsl;
            const unsigned short* wrow = oWt + (size_t)(16 * ns + c16) * 128;
#pragma unroll
            for (int kc = 0; kc < 4; ++kc)
                acc2[nsl] = __builtin_amdgcn_mfma_f32_16x16x32_bf16(
                    as_bf16(af[kc]), as_bf16(*(const s16x8*)&wrow[kc * 32 + 8 * g]),
                    acc2[nsl], 0, 0, 0);
        }
#pragma unroll
        for (int nsl = 0; nsl < 2; ++nsl) {
            const int n = 16 * (wid * 2 + nsl) + c16;
            const float bv = obv[n];
#pragma unroll
            for (int r = 0; r < 4; ++r) {
                const int lr = 4 * g + r;
                xbuf[lr][n] = acc2[nsl][r] + bv + x[(size_t)(m0 + lr) * 128 + n];
            }
        }
    }
    __syncthreads();
    // ---- LN2 (redundant per wave from shared xbuf)
    s16x8 af1[4];
    {
        float v2[4][8];
#pragma unroll
        for (int kc = 0; kc < 4; ++kc) {
            const f32x4 a0 = *(const f32x4*)&xbuf[c16][kc * 32 + 8 * g];
            const f32x4 a1 = *(const f32x4*)&xbuf[c16][kc * 32 + 8 * g + 4];
#pragma unroll
            for (int e = 0; e < 4; ++e) { v2[kc][e] = a0[e]; v2[kc][4 + e] = a1[e]; }
        }
        float s = 0.f;
#pragma unroll
        for (int kc = 0; kc < 4; ++kc)
#pragma unroll
            for (int e = 0; e < 8; ++e) s += v2[kc][e];
        s += __shfl_xor(s, 16, 64); s += __shfl_xor(s, 32, 64);
        const float mean = s * (1.f / 128.f);
        float s2 = 0.f;
#pragma unroll
        for (int kc = 0; kc < 4; ++kc)
#pragma unroll
            for (int e = 0; e < 8; ++e) { const float d = v2[kc][e] - mean; s2 += d * d; }
        s2 += __shfl_xor(s2, 16, 64); s2 += __shfl_xor(s2, 32, 64);
        const float rs = rsqrtf(s2 * (1.f / 128.f) + 1e-5f);
#pragma unroll
        for (int kc = 0; kc < 4; ++kc) {
            union { s16x8 v8; unsigned d[4]; } pk;
#pragma unroll
            for (int j = 0; j < 4; ++j) {
                const int col = kc * 32 + 8 * g + 2 * j;
                const float x0 = (v2[kc][2 * j] - mean) * rs * n2g[col] + n2b[col];
                const float x1 = (v2[kc][2 * j + 1] - mean) * rs * n2g[col + 1] + n2b[col + 1];
                pk.d[j] = f2bf2(x0, x1);
            }
            af1[kc] = pk.v8;
        }
    }
    // ---- FF1 + GELU: ns = 4*wid + {0..3}
    {
        f32x4 accf[4];
#pragma unroll
        for (int z = 0; z < 4; ++z) accf[z] = f32x4{0.f, 0.f, 0.f, 0.f};
#pragma unroll
        for (int nsl = 0; nsl < 4; ++nsl) {
            const int ns = wid * 4 + nsl;
            const unsigned short* wrow = f1Wt + (size_t)(16 * ns + c16) * 128;
#pragma unroll
            for (int kc = 0; kc < 4; ++kc)
                accf[nsl] = __builtin_amdgcn_mfma_f32_16x16x32_bf16(
                    as_bf16(af1[kc]), as_bf16(*(const s16x8*)&wrow[kc * 32 + 8 * g]),
                    accf[nsl], 0, 0, 0);
        }
#pragma unroll
        for (int nsl = 0; nsl < 4; ++nsl) {
            const int n = 16 * (wid * 4 + nsl) + c16;
            const float bv = f1b[n];
#pragma unroll
            for (int r = 0; r < 4; ++r) {
                float vv = accf[nsl][r] + bv;
                vv = vv * 0.5f * (1.0f + erff(vv * 0.70710678118654752f));
                g1buf[4 * g + r][n] = f2bf(vv);
            }
        }
    }
    __syncthreads();
    // ---- FF2: ns = 2*wid + {0,1}, full K=256 from shared g1buf
    float fx[2][4];
    {
        s16x8 af2[8];
#pragma unroll
        for (int kc = 0; kc < 8; ++kc)
            af2[kc] = *(const s16x8*)&g1buf[c16][kc * 32 + 8 * g];
        f32x4 acc2[2];
#pragma unroll
        for (int z = 0; z < 2; ++z) acc2[z] = f32x4{0.f, 0.f, 0.f, 0.f};
#pragma unroll
        for (int nsl = 0; nsl < 2; ++nsl) {
            const int ns = wid * 2 + nsl;
            const unsigned short* wrow = f2Wt + (size_t)(16 * ns + c16) * 256;
#pragma unroll
            for (int kc = 0; kc < 8; ++kc)
                acc2[nsl] = __builtin_amdgcn_mfma_f32_16x16x32_bf16(
                    as_bf16(af2[kc]), as_bf16(*(const s16x8*)&wrow[kc * 32 + 8 * g]),
                    acc2[nsl], 0, 0, 0);
        }
#pragma unroll
        for (int nsl = 0; nsl < 2; ++nsl) {
            const int n = 16 * (wid * 2 + nsl) + c16;
            const float bv = f2b[n];
#pragma unroll
            for (int r = 0; r < 4; ++r)
                fx[nsl][r] = acc2[nsl][r] + bv + xbuf[4 * g + r][n];
        }
    }
    if (!QKV && !LAST) {
#pragma unroll
        for (int nsl = 0; nsl < 2; ++nsl) {
            const int n = 16 * (wid * 2 + nsl) + c16;
#pragma unroll
            for (int r = 0; r < 4; ++r)
                x[(size_t)(m0 + 4 * g + r) * 128 + n] = fx[nsl][r];
        }
        return;
    }
    // write fx into xbuf (own cols only; disjoint across waves)
#pragma unroll
    for (int nsl = 0; nsl < 2; ++nsl) {
        const int n = 16 * (wid * 2 + nsl) + c16;
#pragma unroll
        for (int r = 0; r < 4; ++r) {
            const int lr = 4 * g + r;
            if (QKV) x[(size_t)(m0 + lr) * 128 + n] = fx[nsl][r];
            xbuf[lr][n] = fx[nsl][r];
        }
    }
    __syncthreads();
    if (QKV) {
        // ---- fused layer-1 LN1 (redundant per wave) -> A-frags
        s16x8 afq[4];
        {
            float v1[4][8];
#pragma unroll
            for (int kc = 0; kc < 4; ++kc) {
                const f32x4 a0 = *(const f32x4*)&xbuf[c16][kc * 32 + 8 * g];
                const f32x4 a1 = *(const f32x4*)&xbuf[c16][kc * 32 + 8 * g + 4];
#pragma unroll
                for (int e = 0; e < 4; ++e) { v1[kc][e] = a0[e]; v1[kc][4 + e] = a1[e]; }
            }
            float s1 = 0.f;
#pragma unroll
            for (int kc = 0; kc < 4; ++kc)
#pragma unroll
                for (int e = 0; e < 8; ++e) s1 += v1[kc][e];
            s1 += __shfl_xor(s1, 16, 64); s1 += __shfl_xor(s1, 32, 64);
            const float mean1 = s1 * (1.f / 128.f);
            float sq1 = 0.f;
#pragma unroll
            for (int kc = 0; kc < 4; ++kc)
#pragma unroll
                for (int e = 0; e < 8; ++e) { const float d = v1[kc][e] - mean1; sq1 += d * d; }
            sq1 += __shfl_xor(sq1, 16, 64); sq1 += __shfl_xor(sq1, 32, 64);
            const float rs1 = rsqrtf(sq1 * (1.f / 128.f) + 1e-5f);
#pragma unroll
            for (int kc = 0; kc < 4; ++kc) {
                union { s16x8 v8; unsigned d[4]; } pk;
#pragma unroll
                for (int j = 0; j < 4; ++j) {
                    const int col = kc * 32 + 8 * g + 2 * j;
                    const float x0 = (v1[kc][2 * j] - mean1) * rs1 * n1g2[col] + n1b2[col];
                    const float x1 = (v1[kc][2 * j + 1] - mean1) * rs1 * n1g2[col + 1] + n1b2[col + 1];
                    pk.d[j] = f2bf2(x0, x1);
                }
                afq[kc] = pk.v8;
            }
        }
        // ---- layer-1 qkv: 24 ns, 6 per wave
#pragma unroll
        for (int j = 0; j < 6; ++j) {
            const int ns = wid * 6 + j;
            const unsigned short* wrow = w2 + (size_t)(ns * 16 + c16) * 128;
            f32x4 acc = f32x4{0.f, 0.f, 0.f, 0.f};
#pragma unroll
            for (int kc = 0; kc < 4; ++kc)
                acc = __builtin_amdgcn_mfma_f32_16x16x32_bf16(
                    as_bf16(afq[kc]), as_bf16(*(const s16x8*)&wrow[kc * 32 + 8 * g]),
                    acc, 0, 0, 0);
            const int n = ns * 16 + c16;
            const float bv = bcat2[n];
            if (ns >= 16) {
                const int row0 = m0 + 4 * g;
                u16x4 pk;
#pragma unroll
                for (int r = 0; r < 4; ++r) pk[r] = f2bf(acc[r] + bv);
                *(u16x4*)&vtbuf[(size_t)(n - 256) * 8192 + row0] = pk;
            } else {
#pragma unroll
                for (int r = 0; r < 4; ++r)
                    qk[(size_t)(m0 + 4 * g + r) * 256 + n] = f2bf(acc[r] + bv);
            }
        }
        return;
    }
    // ---- LAST: cooperative row stats (4 rows/wave) then disjoint col partials
    if (LAST) {
#pragma unroll
        for (int rr = 0; rr < 4; ++rr) {
            const int row = wid * 4 + rr;
            const float v0 = xbuf[row][l], v1 = xbuf[row][l + 64];
            const float s = wave_sum64(v0 + v1);
            const float mean = s * (1.f / 128.f);
            const float d0 = v0 - mean, d1 = v1 - mean;
            const float s2 = wave_sum64(d0 * d0 + d1 * d1);
            const float rstd = rsqrtf(s2 * (1.f / 128.f) + 1e-5f);
            if (l == 0) { stats[row][0] = mean; stats[row][1] = rstd; }
        }
        __syncthreads();
#pragma unroll
        for (int nsl = 0; nsl < 2; ++nsl) {
            const int ns = wid * 2 + nsl;
            const int n = 16 * ns + c16;
            const float pg = post_g[n], pb_ = post_b[n];
            float cs = 0.f;
#pragma unroll
            for (int r = 0; r < 4; ++r) {
                const int row = 4 * g + r;
                cs += (xbuf[row][n] - stats[row][0]) * stats[row][1] * pg + pb_;
            }
            cs += __shfl_xor(cs, 16, 64);
            cs += __shfl_xor(cs, 32, 64);
            if (l < 16) partial[(size_t)blockIdx.x * 128 + n] = cs;
        }
    }
}

// ---------------------------------------------------------------------------
// Tail B: fused = mean + 0.1*lg; out = fused @ out_W + out_b   (4 blocks)
// ---------------------------------------------------------------------------
__global__ __launch_bounds__(128) void gace_tailB_k(
    const float* __restrict__ partial, const float* __restrict__ lg,
    const float* __restrict__ oW, const float* __restrict__ obv,
    float* __restrict__ out)
{
    const int tid = threadIdx.x, b2 = blockIdx.x;
    __shared__ float fused[128];
    float s = 0.f;
#pragma unroll 8
    for (int c = 0; c < 128; ++c) s += partial[(size_t)(b2 * 128 + c) * 128 + tid];
    fused[tid] = s * (1.f / 2048.f) + 0.1f * lg[b2 * 128 + tid];
    __syncthreads();
    float r = obv[tid];
#pragma unroll 8
    for (int d2 = 0; d2 < 128; ++d2) r += fused[d2] * oW[d2 * 128 + tid];
    out[b2 * 128 + tid] = r;
}

// ---------------------------------------------------------------------------
extern "C" void kernel_launch(void* const* d_in, const int* in_sizes, int n_in,
                              void* d_out, int out_size, void* d_ws, size_t ws_size,
                              hipStream_t stream)
{
    (void)in_sizes; (void)n_in; (void)out_size; (void)ws_size;
    const float* local_global = (const float*)d_in[0];
    const float* task   = (const float*)d_in[1];
    const float* priv   = (const float*)d_in[2];
    const float* dag    = (const float*)d_in[3];
    const float* amask  = (const float*)d_in[4];
    const float* task_W = (const float*)d_in[5];
    const float* task_b = (const float*)d_in[6];
    const float* priv_W = (const float*)d_in[7];
    const float* priv_b = (const float*)d_in[8];
    const float* dag_W  = (const float*)d_in[9];
    const float* dag_b  = (const float*)d_in[10];
    const float* pre_g  = (const float*)d_in[11];
    const float* pre_b  = (const float*)d_in[12];
    const float* post_g = (const float*)d_in[13];
    const float* post_b = (const float*)d_in[14];
    const float* out_W  = (const float*)d_in[15];
    const float* out_b  = (const float*)d_in[16];
    const float* qW = (const float*)d_in[17];
    const float* qb = (const float*)d_in[18];
    const float* kW = (const float*)d_in[19];
    const float* kb = (const float*)d_in[20];
    const float* vW = (const float*)d_in[21];
    const float* vb = (const float*)d_in[22];
    const float* oW = (const float*)d_in[23];
    const float* ob = (const float*)d_in[24];
    const float* n1g = (const float*)d_in[25];
    const float* n1b = (const float*)d_in[26];
    const float* n2g = (const float*)d_in[27];
    const float* n2b = (const float*)d_in[28];
    const float* f1W = (const float*)d_in[29];
    const float* f1b = (const float*)d_in[30];
    const float* f2W = (const float*)d_in[31];
    const float* f2b = (const float*)d_in[32];

    char* ws = (char*)d_ws;
    size_t off = 0;
    auto carve = [&](size_t sz) {
        void* p = ws + off;
        off += (sz + 255) & ~(size_t)255;
        return p;
    };
    unsigned long long* bits = (unsigned long long*)carve(8192ull * 32 * 8);  // 2 MB
    float*          x    = (float*)carve(8192ull * 128 * 4);                   // 4 MB
    unsigned short* qk   = (unsigned short*)carve(8192ull * 256 * 2);          // 4 MB (q|k)
    unsigned short* vt   = (unsigned short*)carve(128ull * 8192 * 2);          // 2 MB (V^T)
    float*          part = (float*)carve(512ull * 128 * 4);                    // 256 KB
    unsigned short* Opb  = (unsigned short*)carve(8ull * 8192 * 128 * 2);      // 16 MB
    float*          mlb  = (float*)carve(8ull * 8192 * 4 * 4);                 // 1 MB
    unsigned short* wbf  = (unsigned short*)carve(2ull * 131072 * 2);          // 512 KB
    float*          bcat = (float*)carve(2ull * 384 * 4);

    gace_setup_k<<<4353, 256, 0, stream>>>(
        amask, bits,
        task, priv, dag, task_W, task_b, priv_W, priv_b, dag_W, dag_b,
        pre_g, pre_b, x,
        qW, kW, vW, oW, f1W, f2W, qb, kb, vb, wbf, bcat);
    // layer 0
    gace_qkv_k<<<dim3(128, 6), 256, 0, stream>>>(
        x, n1g, n1b, wbf, bcat, qk, vt);
    gace_flash8_k<<<1024, 512, 0, stream>>>(qk, vt, bits, Opb, mlb);
    // post(layer 0) fused with qkv(layer 1) — 4-wave n-split blocks
    gace_post2_k<1, 0><<<512, 256, 0, stream>>>(
        Opb, mlb, wbf + 49152, ob, x, n2g, n2b,
        wbf + 65536, f1b, wbf + 98304, f2b,
        n1g + 128, n1b + 128, wbf + 131072, bcat + 384, qk, vt,
        nullptr, nullptr, nullptr);
    // layer 1
    gace_flash8_k<<<1024, 512, 0, stream>>>(qk, vt, bits, Opb, mlb);
    gace_post2_k<0, 1><<<512, 256, 0, stream>>>(
        Opb, mlb, wbf + 131072 + 49152, ob + 128, x, n2g + 128, n2b + 128,
        wbf + 131072 + 65536, f1b + 256, wbf + 131072 + 98304, f2b + 128,
        nullptr, nullptr, nullptr, nullptr, nullptr, nullptr,
        post_g, post_b, part);
    gace_tailB_k<<<4, 128, 0, stream>>>(part, local_global, out_W, out_b, (float*)d_out);
}